// Round 4
// baseline (141.378 us; speedup 1.0000x reference)
//
#include <hip/hip_runtime.h>
#include <hip/hip_bf16.h>
#include <math.h>

// Problem constants
#define BDIM    128   // batch graphs
#define N_NODES 512
#define KNB     10
#define FDIM    128
#define CDIM    40

// ---------------------------------------------------------------------------
// ALGEBRA (verified on-HW R2/R3, absmax 0.0): both SAGE layers are affine and
// only h[:,0,:] is consumed. With A_l/B_l = mp/self halves of w_sage[l]:
//   v1[b] = sum_{k,j} x[b, neigh[b, nb_k, j]]   (nb_k = neigh[b,0,k])
//   v2[b] = sum_k x[b, nb_k]
//   v4[b] = x[b,0]
//   p = A1·(0.01v1) + B1·(0.1v2) + b0
//   q = A1·(0.1v2)  + B1·v4      + b0
//   r = A2·p + B2·q + b1
//   z = L1·r + lin1_b
// then BatchNorm(batch)+ReLU+lin2+softmax.
//
// R4: SINGLE dispatch. Each block computes z[b]; the last block to finish
// (atomicAdd ticket on a memset-zeroed counter) runs the head. No spinning,
// so no co-residency assumption (G16-safe). Reader __threadfence() after the
// ticket invalidates L1 before re-reading z (graph replay can leave stale z
// from the previous iteration in this CU's L1).
// ---------------------------------------------------------------------------

__global__ __launch_bounds__(256) void fused_all(
    const float* __restrict__ x,       // (128,512,128)
    const int*   __restrict__ neigh,   // (128,512,10)
    const float* __restrict__ w_sage,  // (2,128,256)
    const float* __restrict__ b_sage,  // (2,128)
    const float* __restrict__ lin1_w,  // (64,128)
    const float* __restrict__ lin1_b,  // (64)
    const float* __restrict__ gamma,   // (64)
    const float* __restrict__ beta,    // (64)
    const float* __restrict__ w2,      // (40,64)
    const float* __restrict__ b2,      // (40)
    float*       __restrict__ z,       // (128,64) workspace
    unsigned int* __restrict__ cnt,    // zeroed by memset node
    float*       __restrict__ out)     // (128,40)
{
    __shared__ int   nb0s[16];
    __shared__ int   l2s[112];
    __shared__ float part[2][2][128];
    __shared__ float vs0[128], vs1[128], vs2[128];
    __shared__ float pv[128], qv[128], rv[128];
    __shared__ float zpart[4][64];
    __shared__ int   is_last;

    const int b   = blockIdx.x;
    const int tid = threadIdx.x;
    const int f   = tid & 127;
    const int h   = tid >> 7;
    const int* nbB = neigh + b * (N_NODES * KNB);
    const float* xb = x + (size_t)b * (N_NODES * FDIM);

    // ---- stage 0: issue independent v4 load FIRST, then the index chain ----
    float v4early = 0.f;
    if (h == 0) v4early = xb[f];                   // x[b,0,f] — no deps
    if (tid < 10) nb0s[tid] = nbB[tid];            // neigh[b,0,:]
    __syncthreads();
    if (tid < 100) {
        int k = tid / 10, jj = tid - k * 10;
        l2s[tid] = nbB[nb0s[k] * KNB + jj];        // neigh[b, nb_k, jj]
    }
    __syncthreads();

    // ---- stage 1: gather-sum v1, v2 (deep ILP: 25 loads in flight) ----
    {
        float s1 = 0.f, s2 = 0.f;
        #pragma unroll 25
        for (int t = h * 50; t < h * 50 + 50; ++t) s1 += xb[l2s[t] * FDIM + f];
        #pragma unroll
        for (int k = h * 5; k < h * 5 + 5; ++k)    s2 += xb[nb0s[k] * FDIM + f];
        part[0][h][f] = s1;
        part[1][h][f] = s2;
    }
    __syncthreads();
    if (h == 0) {
        vs0[f] = (part[0][0][f] + part[0][1][f]) * 0.01f;   // 0.01*v1
        vs1[f] = (part[1][0][f] + part[1][1][f]) * 0.1f;    // 0.1*v2
        vs2[f] = v4early;                                   // v4
    }
    __syncthreads();

    // ---- stage 2: p = A1*vs0 + B1*vs1, q = A1*vs1 + B1*vs2 ----
    {
        const int g = tid & 127, half = tid >> 7;
        const float4* w4 = (const float4*)(w_sage + g * 256);
        float p0 = 0.f, p1 = 0.f, q0 = 0.f, q1 = 0.f;
        #pragma unroll
        for (int i = 0; i < 16; ++i) {
            int f4 = half * 16 + i;          // A1 segment
            float4 w = w4[f4];
            int fb = f4 * 4;
            p0 = fmaf(w.x, vs0[fb + 0], p0); p1 = fmaf(w.y, vs0[fb + 1], p1);
            p0 = fmaf(w.z, vs0[fb + 2], p0); p1 = fmaf(w.w, vs0[fb + 3], p1);
            q0 = fmaf(w.x, vs1[fb + 0], q0); q1 = fmaf(w.y, vs1[fb + 1], q1);
            q0 = fmaf(w.z, vs1[fb + 2], q0); q1 = fmaf(w.w, vs1[fb + 3], q1);
        }
        #pragma unroll
        for (int i = 0; i < 16; ++i) {
            int f4 = 32 + half * 16 + i;     // B1 segment
            float4 w = w4[f4];
            int fb = (f4 - 32) * 4;
            p0 = fmaf(w.x, vs1[fb + 0], p0); p1 = fmaf(w.y, vs1[fb + 1], p1);
            p0 = fmaf(w.z, vs1[fb + 2], p0); p1 = fmaf(w.w, vs1[fb + 3], p1);
            q0 = fmaf(w.x, vs2[fb + 0], q0); q1 = fmaf(w.y, vs2[fb + 1], q1);
            q0 = fmaf(w.z, vs2[fb + 2], q0); q1 = fmaf(w.w, vs2[fb + 3], q1);
        }
        part[0][half][g] = p0 + p1;
        part[1][half][g] = q0 + q1;
    }
    __syncthreads();
    if (h == 0) {
        float b0 = b_sage[f];
        pv[f] = part[0][0][f] + part[0][1][f] + b0;
        qv[f] = part[1][0][f] + part[1][1][f] + b0;
    }
    __syncthreads();

    // ---- stage 3: r = A2*p + B2*q + b1 ----
    {
        const int g2 = tid & 127, half = tid >> 7;
        const float4* w4 = (const float4*)(w_sage + 32768 + g2 * 256 + half * 128);
        const float* vv = half ? qv : pv;
        float a0 = 0.f, a1 = 0.f;
        #pragma unroll
        for (int i = 0; i < 32; ++i) {
            float4 w = w4[i];
            int gb = i * 4;
            a0 = fmaf(w.x, vv[gb + 0], a0); a1 = fmaf(w.y, vv[gb + 1], a1);
            a0 = fmaf(w.z, vv[gb + 2], a0); a1 = fmaf(w.w, vv[gb + 3], a1);
        }
        part[0][half][g2] = a0 + a1;
    }
    __syncthreads();
    if (h == 0) rv[f] = b_sage[128 + f] + part[0][0][f] + part[0][1][f];
    __syncthreads();

    // ---- stage 4: z = L1*r + lin1_b ----
    {
        const int j = tid & 63, qt = tid >> 6;
        const float4* w4 = (const float4*)(lin1_w + j * 128 + qt * 32);
        float a0 = 0.f, a1 = 0.f;
        #pragma unroll
        for (int i = 0; i < 8; ++i) {
            float4 w = w4[i];
            int gb = qt * 32 + i * 4;
            a0 = fmaf(w.x, rv[gb + 0], a0); a1 = fmaf(w.y, rv[gb + 1], a1);
            a0 = fmaf(w.z, rv[gb + 2], a0); a1 = fmaf(w.w, rv[gb + 3], a1);
        }
        zpart[qt][j] = a0 + a1;
    }
    __syncthreads();
    if (tid < 64)
        z[b * 64 + tid] = lin1_b[tid] + zpart[0][tid] + zpart[1][tid]
                        + zpart[2][tid] + zpart[3][tid];

    // ---- ticket: last block to arrive runs the head ----
    __threadfence();                       // release z[b]
    if (tid == 0) {
        unsigned int old = atomicAdd(cnt, 1u);   // device-scope
        is_last = (old == (unsigned int)(BDIM - 1));
    }
    __syncthreads();
    if (!is_last) return;
    __threadfence();                       // acquire: invalidate L1 (stale z
                                           // from previous graph replay!)

    // ================= HEAD (256 threads) =================
    __shared__ float zs[128][65];
    __shared__ float sc[64], sh[64];

    for (int i = 0; i < 32; ++i) {
        int idx = i * 256 + tid;
        zs[idx >> 6][idx & 63] = z[idx];
    }
    __syncthreads();

    if (tid < 64) {
        float s = 0.f, ss = 0.f;
        for (int i = 0; i < 128; ++i) {
            float v = zs[i][tid];
            s += v; ss += v * v;
        }
        float mu  = s * (1.f / 128.f);
        float var = ss * (1.f / 128.f) - mu * mu;
        float rs  = rsqrtf(var + 1e-5f) * gamma[tid];
        sc[tid] = rs;
        sh[tid] = beta[tid] - mu * rs;
    }
    __syncthreads();

    {
        int j = tid & 63;
        for (int i = tid >> 6; i < 128; i += 4) {
            float v = fmaf(zs[i][j], sc[j], sh[j]);
            zs[i][j] = fmaxf(v, 0.f);
        }
    }
    __syncthreads();

    if (tid < 128) {
        int i = tid;
        float lg[CDIM];
        float mx = -1e30f;
        #pragma unroll 4
        for (int c = 0; c < CDIM; ++c) {
            const float* w = w2 + c * 64;
            float s = b2[c];
            for (int ff = 0; ff < 64; ++ff) s = fmaf(zs[i][ff], w[ff], s);
            lg[c] = s;
            mx = fmaxf(mx, s);
        }
        float den = 0.f;
        for (int c = 0; c < CDIM; ++c) {
            lg[c] = __expf(lg[c] - mx);
            den += lg[c];
        }
        float inv = 1.f / den;
        for (int c = 0; c < CDIM; ++c) out[i * CDIM + c] = lg[c] * inv;
    }
}

// ---------------------------------------------------------------------------
extern "C" void kernel_launch(void* const* d_in, const int* in_sizes, int n_in,
                              void* d_out, int out_size, void* d_ws, size_t ws_size,
                              hipStream_t stream)
{
    const float* x      = (const float*)d_in[0];
    const int*   neigh  = (const int*)  d_in[1];
    const float* w_sage = (const float*)d_in[2];
    const float* b_sage = (const float*)d_in[3];
    const float* lin1_w = (const float*)d_in[4];
    const float* lin1_b = (const float*)d_in[5];
    const float* bn_g   = (const float*)d_in[6];
    const float* bn_b   = (const float*)d_in[7];
    const float* lin2_w = (const float*)d_in[8];
    const float* lin2_b = (const float*)d_in[9];
    float* out = (float*)d_out;

    float* z = (float*)d_ws;                       // 128*64 floats
    unsigned int* cnt = (unsigned int*)(z + BDIM * 64);

    // d_ws is re-poisoned to 0xAA before every launch -> zero the ticket
    // counter with a sanctioned async memset node (harness uses the same API).
    hipMemsetAsync(cnt, 0, sizeof(unsigned int), stream);

    fused_all<<<BDIM, 256, 0, stream>>>(x, neigh, w_sage, b_sage,
                                        lin1_w, lin1_b, bn_g, bn_b,
                                        lin2_w, lin2_b, z, cnt, out);
}

// Round 5
// 131.238 us; speedup vs baseline: 1.0773x; 1.0773x over previous
//
#include <hip/hip_runtime.h>
#include <hip/hip_bf16.h>
#include <math.h>

// Problem constants
#define BDIM    128   // batch graphs
#define N_NODES 512
#define KNB     10
#define FDIM    128
#define CDIM    40

// ---------------------------------------------------------------------------
// ALGEBRA (verified on-HW R2/R3/R4, absmax 0.0): both SAGE layers are affine
// and only h[:,0,:] is consumed. With A_l/B_l = mp/self halves of w_sage[l]:
//   v1[b] = sum_{k,j} x[b, neigh[b, nb_k, j]]   (nb_k = neigh[b,0,k])
//   v2[b] = sum_k x[b, nb_k]
//   v4[b] = x[b,0]
//   p = A1·(0.01v1) + B1·(0.1v2) + b0
//   q = A1·(0.1v2)  + B1·v4      + b0
//   r = A2·p + B2·q + b1
//   z = L1·r + lin1_b
// then BatchNorm(batch)+ReLU+lin2+softmax.
//
// R5: two dispatches (R4's ticket+__threadfence fusion REGRESSED: device-
// scope fences on 8 non-coherent XCD L2s cost more than the saved launch).
// fused_z now uses 512 threads/block: every latency-bound phase splits 4-8
// ways -> 2x waves/CU and <=half the per-thread load chain. The kernel is
// pure latency (R4: 75 GB/s effective, VALUBusy <1%) -- MLP is the lever.
// ---------------------------------------------------------------------------

__global__ __launch_bounds__(512) void fused_z(
    const float* __restrict__ x,       // (128,512,128)
    const int*   __restrict__ neigh,   // (128,512,10)
    const float* __restrict__ w_sage,  // (2,128,256)
    const float* __restrict__ b_sage,  // (2,128)
    const float* __restrict__ lin1_w,  // (64,128)
    const float* __restrict__ lin1_b,  // (64)
    float*       __restrict__ z)       // (128,64)
{
    __shared__ int   nb0s[16];
    __shared__ int   l2s[112];
    __shared__ float scr[8][128];      // reused partial-sum scratch
    __shared__ float vs0[128], vs1[128], vs2[128];
    __shared__ float pv[128], qv[128], rv[128];

    const int b   = blockIdx.x;
    const int tid = threadIdx.x;
    const int f   = tid & 127;
    const int h   = tid >> 7;          // 0..3
    const int* nbB = neigh + b * (N_NODES * KNB);
    const float* xb = x + (size_t)b * (N_NODES * FDIM);

    // ---- stage 0: independent v4 load first, then the 2-hop index chain ----
    float v4early = (h == 0) ? xb[f] : 0.f;      // x[b,0,f] — no deps
    if (tid < 10) nb0s[tid] = nbB[tid];          // neigh[b,0,:]
    __syncthreads();
    if (tid < 100) {
        int k = tid / 10, jj = tid - k * 10;
        l2s[tid] = nbB[nb0s[k] * KNB + jj];      // neigh[b, nb_k, jj]
    }
    __syncthreads();

    // ---- stage 1: gather-sum v1 (25 rows/thread), v2 (5 rows, h<2) ----
    {
        float s1 = 0.f;
        #pragma unroll
        for (int t = h * 25; t < h * 25 + 25; ++t) s1 += xb[l2s[t] * FDIM + f];
        scr[h][f] = s1;
        if (h < 2) {
            float s2 = 0.f;
            #pragma unroll
            for (int k = h * 5; k < h * 5 + 5; ++k) s2 += xb[nb0s[k] * FDIM + f];
            scr[4 + h][f] = s2;
        }
    }
    __syncthreads();
    if (h == 0) {
        vs0[f] = (scr[0][f] + scr[1][f] + scr[2][f] + scr[3][f]) * 0.01f;
        vs1[f] = (scr[4][f] + scr[5][f]) * 0.1f;
        vs2[f] = v4early;
    }
    __syncthreads();

    // ---- stage 2: p = A1*vs0 + B1*vs1, q = A1*vs1 + B1*vs2 ----
    // thread (g=f, half=h): row g of w_sage layer 0, f-range [h*32, h*32+32)
    {
        const float4* w4 = (const float4*)(w_sage + f * 256);
        float p0 = 0.f, p1 = 0.f, q0 = 0.f, q1 = 0.f;
        #pragma unroll
        for (int i = 0; i < 8; ++i) {
            int f4 = h * 8 + i;              // A1 segment
            float4 w = w4[f4];
            int fb = f4 * 4;
            p0 = fmaf(w.x, vs0[fb + 0], p0); p1 = fmaf(w.y, vs0[fb + 1], p1);
            p0 = fmaf(w.z, vs0[fb + 2], p0); p1 = fmaf(w.w, vs0[fb + 3], p1);
            q0 = fmaf(w.x, vs1[fb + 0], q0); q1 = fmaf(w.y, vs1[fb + 1], q1);
            q0 = fmaf(w.z, vs1[fb + 2], q0); q1 = fmaf(w.w, vs1[fb + 3], q1);
        }
        #pragma unroll
        for (int i = 0; i < 8; ++i) {
            int f4 = 32 + h * 8 + i;         // B1 segment
            float4 w = w4[f4];
            int fb = (f4 - 32) * 4;
            p0 = fmaf(w.x, vs1[fb + 0], p0); p1 = fmaf(w.y, vs1[fb + 1], p1);
            p0 = fmaf(w.z, vs1[fb + 2], p0); p1 = fmaf(w.w, vs1[fb + 3], p1);
            q0 = fmaf(w.x, vs2[fb + 0], q0); q1 = fmaf(w.y, vs2[fb + 1], q1);
            q0 = fmaf(w.z, vs2[fb + 2], q0); q1 = fmaf(w.w, vs2[fb + 3], q1);
        }
        scr[h][f]     = p0 + p1;
        scr[4 + h][f] = q0 + q1;
    }
    __syncthreads();
    if (h == 0) {
        float b0 = b_sage[f];
        pv[f] = scr[0][f] + scr[1][f] + scr[2][f] + scr[3][f] + b0;
        qv[f] = scr[4][f] + scr[5][f] + scr[6][f] + scr[7][f] + b0;
    }
    __syncthreads();

    // ---- stage 3: r = A2*p + B2*q + b1 ----
    // quarter h: 0,1 -> A2 f-halves with pv; 2,3 -> B2 f-halves with qv
    {
        const float4* w4 = (const float4*)(w_sage + 32768 + f * 256);
        const float* vv  = (h < 2) ? pv : qv;
        const int fb0    = (h & 1) * 64;
        float a0 = 0.f, a1 = 0.f;
        #pragma unroll
        for (int i = 0; i < 16; ++i) {
            float4 w = w4[h * 16 + i];
            int gb = fb0 + i * 4;
            a0 = fmaf(w.x, vv[gb + 0], a0); a1 = fmaf(w.y, vv[gb + 1], a1);
            a0 = fmaf(w.z, vv[gb + 2], a0); a1 = fmaf(w.w, vv[gb + 3], a1);
        }
        scr[h][f] = a0 + a1;
    }
    __syncthreads();
    if (h == 0) rv[f] = b_sage[128 + f] + scr[0][f] + scr[1][f]
                      + scr[2][f] + scr[3][f];
    __syncthreads();

    // ---- stage 4: z = L1*r + lin1_b (8-way split) ----
    {
        const int j = tid & 63, oct = tid >> 6;     // oct 0..7
        const float4* w4 = (const float4*)(lin1_w + j * 128);
        float a0 = 0.f, a1 = 0.f;
        #pragma unroll
        for (int i = 0; i < 4; ++i) {
            float4 w = w4[oct * 4 + i];
            int gb = oct * 16 + i * 4;
            a0 = fmaf(w.x, rv[gb + 0], a0); a1 = fmaf(w.y, rv[gb + 1], a1);
            a0 = fmaf(w.z, rv[gb + 2], a0); a1 = fmaf(w.w, rv[gb + 3], a1);
        }
        ((float*)scr)[oct * 64 + j] = a0 + a1;
    }
    __syncthreads();
    if (tid < 64) {
        const float* zp = (const float*)scr;
        float acc = lin1_b[tid];
        #pragma unroll
        for (int o = 0; o < 8; ++o) acc += zp[o * 64 + tid];
        z[b * 64 + tid] = acc;
    }
}

// ---------------------------------------------------------------------------
// BatchNorm (over batch) + ReLU + lin2 + softmax. Single block. (verified R1)
// ---------------------------------------------------------------------------
__global__ __launch_bounds__(128) void head_kernel(
    const float* __restrict__ z,      // (128, 64)
    const float* __restrict__ gamma,  // (64)
    const float* __restrict__ beta,   // (64)
    const float* __restrict__ w2,     // (40, 64)
    const float* __restrict__ b2,     // (40)
    float*       __restrict__ out)    // (128, 40)
{
    __shared__ float zs[128][65];
    __shared__ float sc[64], sh[64];
    const int tid = threadIdx.x;

    for (int i = 0; i < 64; ++i) {
        int idx = i * 128 + tid;
        zs[idx >> 6][idx & 63] = z[idx];
    }
    __syncthreads();

    if (tid < 64) {
        float s = 0.f, ss = 0.f;
        for (int i = 0; i < 128; ++i) {
            float v = zs[i][tid];
            s += v; ss += v * v;
        }
        float mu  = s * (1.f / 128.f);
        float var = ss * (1.f / 128.f) - mu * mu;
        float rs  = rsqrtf(var + 1e-5f) * gamma[tid];
        sc[tid] = rs;
        sh[tid] = beta[tid] - mu * rs;
    }
    __syncthreads();

    {
        int j = tid & 63;
        for (int i = tid >> 6; i < 128; i += 2) {
            float v = fmaf(zs[i][j], sc[j], sh[j]);
            zs[i][j] = fmaxf(v, 0.f);
        }
    }
    __syncthreads();

    {
        int i = tid;
        float lg[CDIM];
        float mx = -1e30f;
        #pragma unroll 4
        for (int c = 0; c < CDIM; ++c) {
            const float* w = w2 + c * 64;
            float s = b2[c];
            for (int ff = 0; ff < 64; ++ff) s = fmaf(zs[i][ff], w[ff], s);
            lg[c] = s;
            mx = fmaxf(mx, s);
        }
        float den = 0.f;
        for (int c = 0; c < CDIM; ++c) {
            lg[c] = __expf(lg[c] - mx);
            den += lg[c];
        }
        float inv = 1.f / den;
        for (int c = 0; c < CDIM; ++c) out[i * CDIM + c] = lg[c] * inv;
    }
}

// ---------------------------------------------------------------------------
extern "C" void kernel_launch(void* const* d_in, const int* in_sizes, int n_in,
                              void* d_out, int out_size, void* d_ws, size_t ws_size,
                              hipStream_t stream)
{
    const float* x      = (const float*)d_in[0];
    const int*   neigh  = (const int*)  d_in[1];
    const float* w_sage = (const float*)d_in[2];
    const float* b_sage = (const float*)d_in[3];
    const float* lin1_w = (const float*)d_in[4];
    const float* lin1_b = (const float*)d_in[5];
    const float* bn_g   = (const float*)d_in[6];
    const float* bn_b   = (const float*)d_in[7];
    const float* lin2_w = (const float*)d_in[8];
    const float* lin2_b = (const float*)d_in[9];
    float* out = (float*)d_out;

    float* z = (float*)d_ws;   // 128*64 floats

    fused_z    <<<BDIM, 512, 0, stream>>>(x, neigh, w_sage, b_sage,
                                          lin1_w, lin1_b, z);
    head_kernel<<<1, 128, 0, stream>>>(z, bn_g, bn_b, lin2_w, lin2_b, out);
}